// Round 8
// baseline (451.308 us; speedup 1.0000x reference)
//
#include <hip/hip_runtime.h>
#include <cmath>
#include <cstdint>

#define NTOK   16384
#define NEXP   8
#define DM     512
#define LOG100 4.605170185988092f

typedef _Float16 half8  __attribute__((ext_vector_type(8)));
typedef float    floatx4 __attribute__((ext_vector_type(4)));

#define MFMA_F16(a, b, c) __builtin_amdgcn_mfma_f32_16x16x32_f16((a), (b), (c), 0, 0, 0)

__device__ __forceinline__ void gl_lds16(const void* g, void* l) {
    __builtin_amdgcn_global_load_lds(
        (const __attribute__((address_space(1))) void*)g,
        (__attribute__((address_space(3))) void*)l, 16, 0, 0);
}

__device__ __forceinline__ void atomAddF(float* p, float v) {
#if __has_builtin(__builtin_amdgcn_global_atomic_fadd_f32)
    __builtin_amdgcn_global_atomic_fadd_f32((__attribute__((address_space(1))) float*)p, v);
#else
    atomicAdd(p, v);
#endif
}

// ---------------- ws layout ----------------
// ctrl floats @ws: [0..31] int cnt[2][16] | [32..47] imp[2][8] | [48..49] vq[2]
//                  [50..51] tsc[2] | [52..67] ia[2][8] | [128..8319] rmn[16*512]
// @ws+64KB:  float2 wts[2][16384]  (256KB)
// @ws+384KB: float2 bs[2][16384]   (256KB)
// @ws+704KB: uchar key[2][2][16384] (64KB)
// @ws+1MB:   w0pk 8MB | w1pk 4MB | h16 16MB | bkt(ushort) 2MB  => 31MB total
// xpk (32MB) lives in d_out's h1 region (dead until layer-1 GEMM).

// =============================== W pre-pack + prep (merged) ===============================
__global__ __launch_bounds__(256) void pack_w_kernel(
    const float* __restrict__ W0, const float* __restrict__ W1,
    half8* __restrict__ w0pk, half8* __restrict__ w1pk,
    const float* __restrict__ rm0, const float* __restrict__ rm1,
    const float* __restrict__ ca0, const float* __restrict__ ca1,
    const float* __restrict__ temp0, const float* __restrict__ temp1,
    float* __restrict__ ctrl, float* __restrict__ rmn)
{
    if (blockIdx.x == 3072) {       // ---- prep ----
        int tid = threadIdx.x, lane = tid & 63, w = tid >> 6;
        if (tid < 32) ((int*)ctrl)[tid] = 0;
        if (tid >= 32 && tid < 48) ctrl[tid] = 0.f;
        if (tid == 48 || tid == 49) ctrl[tid] = 0.f;
        if (tid == 50) ctrl[50] = expf(fminf(temp0[0], LOG100));
        if (tid == 51) ctrl[51] = expf(fminf(temp1[0], LOG100));
        if (tid >= 52 && tid < 68) {
            int i = tid - 52;
            ctrl[tid] = expf(fminf(i < 8 ? ca0[i] : ca1[i - 8], LOG100));
        }
        for (int r = w; r < 16; r += 4) {
            const float* src = (r < 8) ? (rm0 + r * DM) : (rm1 + (r - 8) * DM);
            float v[8]; float ss = 0.f;
            #pragma unroll
            for (int j = 0; j < 8; ++j) { v[j] = src[lane + 64 * j]; ss += v[j] * v[j]; }
            #pragma unroll
            for (int off = 32; off > 0; off >>= 1) ss += __shfl_xor(ss, off);
            float inv = 1.f / fmaxf(sqrtf(ss), 1e-12f);
            float* dst = rmn + r * DM;
            #pragma unroll
            for (int j = 0; j < 8; ++j) dst[lane + 64 * j] = v[j] * inv;
        }
        return;
    }
    int i = blockIdx.x * 256 + threadIdx.x;
    if (i < 512 * 1024) {
        int l = i & 63, j = (i >> 6) & 15, kb = (i >> 10) & 15, nt = (i >> 14) & 3, e = i >> 16;
        int s = l >> 3, p = l & 7, c = p ^ s;
        int n = nt * 128 + j * 8 + s;
        int k = kb * 32 + (c & 3) * 8;
        const float* src = W0 + ((size_t)e * DM + n) * DM + k;
        half8 v;
        #pragma unroll
        for (int t = 0; t < 8; ++t) {
            float f = src[t];
            _Float16 h = (_Float16)f;
            v[t] = (c < 4) ? h : (_Float16)(f - (float)h);
        }
        w0pk[i] = v;
    } else {
        int m = i - 512 * 1024;
        int l = m & 63, j = (m >> 6) & 15, kb = (m >> 10) & 7, nt = (m >> 13) & 3, e = m >> 15;
        int s = l >> 3, p = l & 7, c = p ^ s;
        int n = nt * 128 + j * 8 + s;
        int k = kb * 64 + c * 8;
        const float* src = W1 + ((size_t)e * DM + n) * DM + k;
        half8 v;
        #pragma unroll
        for (int t = 0; t < 8; ++t) v[t] = (_Float16)src[t];
        w1pk[m] = v;
    }
}

// =============================== routing (1 token / wave) ===============================
__global__ __launch_bounds__(256) void route_kernel(
    const float* __restrict__ src,
    const float* __restrict__ rmn,
    int relu_in, int split,
    _Float16* __restrict__ dst,
    unsigned char* __restrict__ key,
    float2* __restrict__ wts,
    float2* __restrict__ bs,
    float* __restrict__ zrow)
{
    __shared__ float rmLds[NEXP * DM];
    int tid = threadIdx.x;
    for (int i = tid; i < NEXP * DM; i += 256) rmLds[i] = rmn[i];
    __syncthreads();
    int lane = tid & 63, w = tid >> 6;
    int token = blockIdx.x * 4 + w;

    {
        float4 z4 = {0.f, 0.f, 0.f, 0.f};
        float4* zp = (float4*)(zrow + (size_t)token * DM);
        zp[lane] = z4;
        zp[lane + 64] = z4;
    }

    const float* row = src + (size_t)token * DM;
    float x[8]; float ss = 0.f;
    #pragma unroll
    for (int j = 0; j < 8; ++j) {
        float v = row[lane + 64 * j];
        if (relu_in) v = fmaxf(v, 0.f);
        x[j] = v; ss += v * v;
    }
    if (split) {
        #pragma unroll
        for (int j = 0; j < 8; ++j) {
            int k = lane + 64 * j;
            size_t base = (size_t)token * 1024 + (size_t)((k >> 5) << 6) + (k & 31);
            _Float16 h = (_Float16)x[j];
            dst[base] = h;
            dst[base + 32] = (_Float16)(x[j] - (float)h);
        }
    } else {
        #pragma unroll
        for (int j = 0; j < 8; ++j)
            dst[(size_t)token * DM + lane + 64 * j] = (_Float16)x[j];
    }
    float d[8];
    #pragma unroll
    for (int e = 0; e < 8; ++e) {
        float a = 0.f;
        #pragma unroll
        for (int j = 0; j < 8; ++j) a += x[j] * rmLds[e * DM + lane + 64 * j];
        d[e] = a;
    }
    #pragma unroll
    for (int off = 32; off > 0; off >>= 1) {
        ss += __shfl_xor(ss, off);
        #pragma unroll
        for (int e = 0; e < 8; ++e) d[e] += __shfl_xor(d[e], off);
    }
    float inv = 1.f / fmaxf(sqrtf(ss), 1e-12f);
    float best = -1e30f, second = -1e30f; int be = 0, se = 0;
    #pragma unroll
    for (int e = 0; e < 8; ++e) {
        float de = d[e] * inv;
        if (de > best)        { second = best; se = be; best = de; be = e; }
        else if (de > second) { second = de; se = e; }
    }
    float z = expf(second - best);
    float w0 = 1.f / (1.f + z), w1 = z / (1.f + z);
    if (lane == 0) {
        key[token] = (unsigned char)be;
        key[NTOK + token] = (unsigned char)se;
        wts[token] = make_float2(w0, w1);
        bs[token] = make_float2(best, second);
    }
}

// =============================== bucket compaction ===============================
__global__ __launch_bounds__(256) void compact_kernel(
    const unsigned char* __restrict__ key,
    const float2* __restrict__ wts,
    const float2* __restrict__ bs,
    int* __restrict__ cnt,
    unsigned short* __restrict__ bkt,
    float* __restrict__ imp,
    float* __restrict__ vq_acc)
{
    int slot = blockIdx.x >> 3, e = blockIdx.x & 7;
    int chunk = blockIdx.y;
    const unsigned char* k = key + slot * NTOK;
    unsigned short* ob = bkt + (size_t)(slot * 8 + e) * NTOK;
    int tid = threadIdx.x, lane = tid & 63, w = tid >> 6;
    float wsum = 0.f, vqs = 0.f;
    for (int c = 0; c < 8; ++c) {
        int tok = chunk * 2048 + c * 256 + tid;
        bool m = (k[tok] == (unsigned char)e);
        unsigned long long mask = __ballot(m);
        int wcount = __popcll(mask);
        int wbase = 0;
        if (lane == 0 && wcount) wbase = atomicAdd(&cnt[slot * 8 + e], wcount);
        wbase = __shfl(wbase, 0);
        if (m) {
            int pre = __popcll(mask & ((1ull << lane) - 1ull));
            ob[wbase + pre] = (unsigned short)tok;
            float2 wp = wts[tok]; float2 b2 = bs[tok];
            float wv = slot ? wp.y : wp.x;
            wsum += wv;
            vqs  += wv * (slot ? b2.y : b2.x);
        }
    }
    #pragma unroll
    for (int off = 32; off > 0; off >>= 1) {
        wsum += __shfl_xor(wsum, off);
        vqs  += __shfl_xor(vqs, off);
    }
    __shared__ float rw[4], rv[4];
    if (lane == 0) { rw[w] = wsum; rv[w] = vqs; }
    __syncthreads();
    if (tid == 0) {
        atomicAdd(&imp[e], rw[0] + rw[1] + rw[2] + rw[3]);
        atomicAdd(vq_acc, -(rv[0] + rv[1] + rv[2] + rv[3]));
    }
}

// =============================== grouped GEMM — barrier-free + XCD grouping ===============================
// Round-7 structure (1 wave/block, wave-private 16KB LDS, zero s_barrier,
// counted vmcnt(16), A-reg double-buffer) PLUS r3's XCD tile grouping, which
// r7 dropped -- its absence cost an 8x A-panel HBM re-fetch (FETCH 275MB):
// bx decode: xcd = bx&7 (dispatch round-robin), s = bx>>3;
//   t = xcd*66 + (s>>3) -> XCD c owns m-tiles [66c, 66c+66)
//   nt64 = s&7          -> the 8 n-tiles of one m-tile run CONSECUTIVELY on
//                          the same XCD: A panel (128KB) HBM-fetched once,
//                          L2-hit 7x; consecutive t walk the same expert's W
//                          image (L2-resident).
// Tile t -> (bucket b, m0) via prefix over cnt16 with 64-row tiles (<=528).
// B image: j-half (nt64&1)*8 of the packed 128-col tile nt = nt64>>1; XOR
// swizzle uses s=row&7, invariant under the j-offset.
// Ledger per iter: issue A(kb+1)[8] + B(kb+1)[8 gl_lds] = 16 -> vmcnt(16)
// retires iter kb's 16 ops. Last iter vmcnt(0). sched_barrier(0) after waits.
// Epilogue: posted fp32 atomic adds (2 commutative contributions/element).
// SPLIT passes: ah*bh, ah*bl, al*bh. Plain: a0*bh (k0..31), a1*bl (k32..63).
template <bool SPLIT>
__global__ __launch_bounds__(64) void gemm_kernel(
    const _Float16* __restrict__ A,      // SPLIT: xpk [tok][1024] ; else h16 [tok][512]
    const _Float16* __restrict__ Wpk,    // packed tiles
    const float* __restrict__ bias,      // [8][512]
    const float* __restrict__ iav,       // [8]
    const float* __restrict__ tscp,
    const int* __restrict__ cnt16,       // [16] this layer (slot*8+e)
    const unsigned short* __restrict__ bkt, // [16][16384] this layer
    const float2* __restrict__ wts,      // [16384]
    float* __restrict__ outp)
{
    __shared__ __align__(16) _Float16 ldsB[2 * 4096];   // 16KB, wave-private
    __shared__ int tokLds[64];

    int bx = blockIdx.x;
    int xcd = bx & 7, sIdx = bx >> 3;
    int t = xcd * 66 + (sIdx >> 3), nt64 = sIdx & 7;
    int b = -1, m0 = 0, M = 0, acc0 = 0;
    #pragma unroll
    for (int bb = 0; bb < 16; ++bb) {
        int Me = cnt16[bb];
        int ne = (Me + 63) >> 6;
        if (t >= acc0 && t < acc0 + ne) { b = bb; m0 = (t - acc0) << 6; M = Me; }
        acc0 += ne;
    }
    if (b < 0) return;                    // t beyond total tiles
    int slot = b >> 3, e = b & 7;
    int n0 = nt64 << 6;
    int valid = min(64, M - m0);
    int lane = threadIdx.x;
    int q = lane >> 4, l15 = lane & 15;

    tokLds[lane] = bkt[(size_t)b * NTOK + m0 + min(lane, valid - 1)];

    constexpr int KIT = SPLIT ? 16 : 8;
    constexpr int AS  = SPLIT ? 1024 : 512;

    // A fragment base pointers: rows mi*16 + l15 (single wave owns all 64 rows)
    const _Float16* Ab[4];
    #pragma unroll
    for (int mi = 0; mi < 4; ++mi)
        Ab[mi] = A + (size_t)tokLds[mi * 16 + l15] * AS + q * 8;

    // packed W: 128-col tile nt64>>1, take the j-half (nt64&1)*8..+8
    const _Float16* wtile = Wpk + ((size_t)(e * 4 + (nt64 >> 1)) * KIT) * 8192
                                + (size_t)(nt64 & 1) * 8 * 512;

    floatx4 accu[4][4];
    #pragma unroll
    for (int mi = 0; mi < 4; ++mi)
        #pragma unroll
        for (int ni = 0; ni < 4; ++ni) accu[mi][ni] = (floatx4){0.f, 0.f, 0.f, 0.f};

    half8 ahR[2][4], alR[2][4];

    // prologue: A(0) -> reg set 0, B(0) -> LDS buf 0 (8 x 1KB contiguous copies)
    #pragma unroll
    for (int mi = 0; mi < 4; ++mi) {
        ahR[0][mi] = *(const half8*)(Ab[mi]);
        alR[0][mi] = *(const half8*)(Ab[mi] + 32);
    }
    #pragma unroll
    for (int jj = 0; jj < 8; ++jj)
        gl_lds16(wtile + jj * 512 + lane * 8, (void*)(ldsB + jj * 512));

    #pragma unroll
    for (int kb = 0; kb < KIT; ++kb) {
        int cu = kb & 1, nx = cu ^ 1;
        if (kb + 1 < KIT) {
            #pragma unroll
            for (int mi = 0; mi < 4; ++mi) {
                ahR[nx][mi] = *(const half8*)(Ab[mi] + (kb + 1) * 64);
                alR[nx][mi] = *(const half8*)(Ab[mi] + (kb + 1) * 64 + 32);
            }
            const _Float16* wb = wtile + (size_t)(kb + 1) * 8192;
            _Float16* dB = ldsB + nx * 4096;
            #pragma unroll
            for (int jj = 0; jj < 8; ++jj)
                gl_lds16(wb + jj * 512 + lane * 8, (void*)(dB + jj * 512));
            asm volatile("s_waitcnt vmcnt(16)" ::: "memory");   // retire iter-kb's 16 ops
        } else {
            asm volatile("s_waitcnt vmcnt(0)" ::: "memory");
        }
        __builtin_amdgcn_sched_barrier(0);
        {
            const _Float16* bB = ldsB + cu * 4096;
            #pragma unroll
            for (int ni = 0; ni < 4; ++ni) {
                int r = ni * 16 + l15;
                int ph = q ^ (r & 7), pl = (q + 4) ^ (r & 7);
                half8 bh = *(const half8*)(bB + r * 64 + ph * 8);
                half8 bl = *(const half8*)(bB + r * 64 + pl * 8);
                if constexpr (SPLIT) {
                    #pragma unroll
                    for (int mi = 0; mi < 4; ++mi) accu[mi][ni] = MFMA_F16(ahR[cu][mi], bh, accu[mi][ni]);
                    #pragma unroll
                    for (int mi = 0; mi < 4; ++mi) accu[mi][ni] = MFMA_F16(ahR[cu][mi], bl, accu[mi][ni]);
                    #pragma unroll
                    for (int mi = 0; mi < 4; ++mi) accu[mi][ni] = MFMA_F16(alR[cu][mi], bh, accu[mi][ni]);
                } else {
                    #pragma unroll
                    for (int mi = 0; mi < 4; ++mi) accu[mi][ni] = MFMA_F16(ahR[cu][mi], bh, accu[mi][ni]);
                    #pragma unroll
                    for (int mi = 0; mi < 4; ++mi) accu[mi][ni] = MFMA_F16(alR[cu][mi], bl, accu[mi][ni]);
                }
            }
        }
    }

    // epilogue: C/D layout col=lane&15, row=(lane>>4)*4+reg; posted atomic adds
    float tsc = *tscp, iae = iav[e];
    float bv[4];
    #pragma unroll
    for (int ni = 0; ni < 4; ++ni) bv[ni] = bias[e * DM + n0 + ni * 16 + l15];
    #pragma unroll
    for (int mi = 0; mi < 4; ++mi) {
        int liBase = mi * 16 + q * 4;
        #pragma unroll
        for (int reg = 0; reg < 4; ++reg) {
            int li = liBase + reg;
            if (li < valid) {
                int tok = tokLds[li];
                float2 wp = wts[tok];
                float wgt = slot ? wp.y : wp.x;
                float sg = tsc * wgt * iae, sb = tsc * wgt;
                float* orow = outp + (size_t)tok * DM + n0;
                #pragma unroll
                for (int ni = 0; ni < 4; ++ni) {
                    float v = accu[mi][ni][reg] * sg + bv[ni] * sb;
                    int c = ni * 16 + l15;
                    atomAddF(&orow[c], v);
                }
            }
        }
    }
}

// =============================== finalize aux ===============================
__global__ void finalize_kernel(const float* __restrict__ ctrl, float* __restrict__ outp)
{
    if (threadIdx.x == 0) {
        float aux = 0.f;
        for (int l = 0; l < 2; ++l) {
            float vq = ctrl[48 + l] / (float)NTOK;
            float mean = 0.f;
            for (int e = 0; e < 8; ++e) mean += ctrl[32 + l * 8 + e];
            mean *= 0.125f;
            float s = 0.f;
            for (int e = 0; e < 8; ++e) {
                float d = ctrl[32 + l * 8 + e] - mean;
                s += d * d;
            }
            float var = s / 7.f;                       // ddof=1
            float lb = var / (mean * mean + 1e-10f);
            aux += 0.05f * vq + 0.01f * lb;
        }
        *outp = aux;
    }
}

// =============================== launch ===============================
extern "C" void kernel_launch(void* const* d_in, const int* in_sizes, int n_in,
                              void* d_out, int out_size, void* d_ws, size_t ws_size,
                              hipStream_t stream) {
    const float* x     = (const float*)d_in[0];
    const float* rm0   = (const float*)d_in[1];
    const float* W0    = (const float*)d_in[2];
    const float* b0    = (const float*)d_in[3];
    const float* temp0 = (const float*)d_in[4];
    const float* ca0   = (const float*)d_in[5];
    const float* rm1   = (const float*)d_in[6];
    const float* W1    = (const float*)d_in[7];
    const float* b1    = (const float*)d_in[8];
    const float* temp1 = (const float*)d_in[9];
    const float* ca1   = (const float*)d_in[10];
    float* out = (float*)d_out;

    char* ws = (char*)d_ws;
    float* ctrl = (float*)ws;
    int*   cnt  = (int*)ctrl;                 // [2][16]
    float* imp  = ctrl + 32;                  // [2][8]
    float* vq   = ctrl + 48;                  // [2]
    float* tsc  = ctrl + 50;                  // [2]
    float* ia   = ctrl + 52;                  // [2][8]
    float* rmn  = ctrl + 128;                 // [16][512]
    float2*        wts = (float2*)(ws + (size_t)64  * 1024);
    float2*        bs  = (float2*)(ws + (size_t)384 * 1024);
    unsigned char* key = (unsigned char*)(ws + (size_t)704 * 1024);

    char* big = ws + (1 << 20);
    half8*          w0pk8 = (half8*)(big);                                 // 8MB
    half8*          w1pk8 = (half8*)(big + (size_t)8  * 1024 * 1024);      // 4MB
    const _Float16* w0pk  = (const _Float16*)w0pk8;
    const _Float16* w1pk  = (const _Float16*)w1pk8;
    _Float16*       h16   = (_Float16*)(big + (size_t)12 * 1024 * 1024);   // 16MB
    unsigned short* bkt   = (unsigned short*)(big + (size_t)28 * 1024 * 1024); // 2MB

    _Float16* xpk = (_Float16*)(out + (size_t)NTOK * DM);

    // 64-row tiles: 8 XCDs x 66 t-slots x 8 n-tiles (t capacity 528 >= worst 528)
    const int GEMM_GRID = 528 * 8;

    pack_w_kernel<<<3073, 256, 0, stream>>>(W0, W1, w0pk8, w1pk8,
        rm0, rm1, ca0, ca1, temp0, temp1, ctrl, rmn);

    // layer 0
    route_kernel<<<4096, 256, 0, stream>>>(x, rmn, 0, 1, xpk, key, wts, bs, out);
    compact_kernel<<<dim3(16, 8), 256, 0, stream>>>(key, wts, bs, cnt, bkt, imp, vq);
    gemm_kernel<true><<<GEMM_GRID, 64, 0, stream>>>(xpk, w0pk, b0, ia, tsc,
        cnt, bkt, wts, out);

    // layer 1
    route_kernel<<<4096, 256, 0, stream>>>(out, rmn + 4096, 1, 0, h16,
        key + 2 * NTOK, wts + NTOK, bs + NTOK, out + (size_t)NTOK * DM);
    compact_kernel<<<dim3(16, 8), 256, 0, stream>>>(key + 2 * NTOK, wts + NTOK, bs + NTOK,
        cnt + 16, bkt + 16 * NTOK, imp + 8, vq + 1);
    gemm_kernel<false><<<GEMM_GRID, 64, 0, stream>>>(h16, w1pk, b1, ia + 8, tsc + 1,
        cnt + 16, bkt + 16 * NTOK, wts + NTOK, out + (size_t)NTOK * DM);

    finalize_kernel<<<1, 64, 0, stream>>>(ctrl, out + (size_t)2 * NTOK * DM);
}

// Round 9
// 430.168 us; speedup vs baseline: 1.0491x; 1.0491x over previous
//
#include <hip/hip_runtime.h>
#include <cmath>
#include <cstdint>

#define NTOK   16384
#define NEXP   8
#define DM     512
#define LOG100 4.605170185988092f

typedef _Float16 half8  __attribute__((ext_vector_type(8)));
typedef float    floatx4 __attribute__((ext_vector_type(4)));

#define MFMA_F16(a, b, c) __builtin_amdgcn_mfma_f32_16x16x32_f16((a), (b), (c), 0, 0, 0)

__device__ __forceinline__ void gl_lds16(const void* g, void* l) {
    __builtin_amdgcn_global_load_lds(
        (const __attribute__((address_space(1))) void*)g,
        (__attribute__((address_space(3))) void*)l, 16, 0, 0);
}

// ---------------- ws layout ----------------
// ctrl floats @ws: [0..31] int cnt[2][16] | [32..47] imp[2][8] | [48..49] vq[2]
//                  [50..51] tsc[2] | [52..67] ia[2][8] | [128..8319] rmn[16*512]
// @ws+64KB:  float2 wts[2][16384]  (256KB)
// @ws+384KB: float2 bs[2][16384]   (256KB)
// @ws+704KB: uchar key[2][2][16384] (64KB)
// @ws+1MB:   w0pk 8MB | w1pk 4MB | h16 16MB | bkt(ushort) 2MB   (end 31MB)
// @ws+31MB:  Pbuf 32MB (layer-0 slot1 partial, then layer-1 slot1 partial)
//            => ws total 63MB.
// d_out: h_emb region = P0 then final h_emb (in-place sum in route1);
//        h1 region = xpk (route0->gemm0) then Q0 (gemm1) then final h1 (sum1).

// =============================== W pre-pack + prep (merged) ===============================
__global__ __launch_bounds__(256) void pack_w_kernel(
    const float* __restrict__ W0, const float* __restrict__ W1,
    half8* __restrict__ w0pk, half8* __restrict__ w1pk,
    const float* __restrict__ rm0, const float* __restrict__ rm1,
    const float* __restrict__ ca0, const float* __restrict__ ca1,
    const float* __restrict__ temp0, const float* __restrict__ temp1,
    float* __restrict__ ctrl, float* __restrict__ rmn)
{
    if (blockIdx.x == 3072) {       // ---- prep ----
        int tid = threadIdx.x, lane = tid & 63, w = tid >> 6;
        if (tid < 32) ((int*)ctrl)[tid] = 0;
        if (tid >= 32 && tid < 48) ctrl[tid] = 0.f;
        if (tid == 48 || tid == 49) ctrl[tid] = 0.f;
        if (tid == 50) ctrl[50] = expf(fminf(temp0[0], LOG100));
        if (tid == 51) ctrl[51] = expf(fminf(temp1[0], LOG100));
        if (tid >= 52 && tid < 68) {
            int i = tid - 52;
            ctrl[tid] = expf(fminf(i < 8 ? ca0[i] : ca1[i - 8], LOG100));
        }
        for (int r = w; r < 16; r += 4) {
            const float* src = (r < 8) ? (rm0 + r * DM) : (rm1 + (r - 8) * DM);
            float v[8]; float ss = 0.f;
            #pragma unroll
            for (int j = 0; j < 8; ++j) { v[j] = src[lane + 64 * j]; ss += v[j] * v[j]; }
            #pragma unroll
            for (int off = 32; off > 0; off >>= 1) ss += __shfl_xor(ss, off);
            float inv = 1.f / fmaxf(sqrtf(ss), 1e-12f);
            float* dst = rmn + r * DM;
            #pragma unroll
            for (int j = 0; j < 8; ++j) dst[lane + 64 * j] = v[j] * inv;
        }
        return;
    }
    int i = blockIdx.x * 256 + threadIdx.x;
    if (i < 512 * 1024) {
        int l = i & 63, j = (i >> 6) & 15, kb = (i >> 10) & 15, nt = (i >> 14) & 3, e = i >> 16;
        int s = l >> 3, p = l & 7, c = p ^ s;
        int n = nt * 128 + j * 8 + s;
        int k = kb * 32 + (c & 3) * 8;
        const float* src = W0 + ((size_t)e * DM + n) * DM + k;
        half8 v;
        #pragma unroll
        for (int t = 0; t < 8; ++t) {
            float f = src[t];
            _Float16 h = (_Float16)f;
            v[t] = (c < 4) ? h : (_Float16)(f - (float)h);
        }
        w0pk[i] = v;
    } else {
        int m = i - 512 * 1024;
        int l = m & 63, j = (m >> 6) & 15, kb = (m >> 10) & 7, nt = (m >> 13) & 3, e = m >> 15;
        int s = l >> 3, p = l & 7, c = p ^ s;
        int n = nt * 128 + j * 8 + s;
        int k = kb * 64 + c * 8;
        const float* src = W1 + ((size_t)e * DM + n) * DM + k;
        half8 v;
        #pragma unroll
        for (int t = 0; t < 8; ++t) v[t] = (_Float16)src[t];
        w1pk[m] = v;
    }
}

// =============================== routing (1 token / wave) ===============================
// src2 (nullable): h0 = src + src2 (partial-sum fusion for layer 1).
// sumOut (nullable): write pre-relu h0 there (h_emb; may alias src in-place --
// each row is read and written by exactly one thread, read-before-write).
__global__ __launch_bounds__(256) void route_kernel(
    const float* __restrict__ src,
    const float* __restrict__ src2,
    const float* __restrict__ rmn,
    int relu_in, int split,
    _Float16* __restrict__ dst,
    float* __restrict__ sumOut,
    unsigned char* __restrict__ key,
    float2* __restrict__ wts,
    float2* __restrict__ bs)
{
    __shared__ float rmLds[NEXP * DM];
    int tid = threadIdx.x;
    for (int i = tid; i < NEXP * DM; i += 256) rmLds[i] = rmn[i];
    __syncthreads();
    int lane = tid & 63, w = tid >> 6;
    int token = blockIdx.x * 4 + w;

    const float* row  = src + (size_t)token * DM;
    const float* row2 = src2 ? (src2 + (size_t)token * DM) : nullptr;
    float* so = sumOut ? (sumOut + (size_t)token * DM) : nullptr;
    float x[8]; float ss = 0.f;
    #pragma unroll
    for (int j = 0; j < 8; ++j) {
        int k = lane + 64 * j;
        float v = row[k];
        if (row2) v += row2[k];
        if (so) so[k] = v;              // pre-relu h0 (h_emb)
        if (relu_in) v = fmaxf(v, 0.f);
        x[j] = v; ss += v * v;
    }
    if (split) {
        #pragma unroll
        for (int j = 0; j < 8; ++j) {
            int k = lane + 64 * j;
            size_t base = (size_t)token * 1024 + (size_t)((k >> 5) << 6) + (k & 31);
            _Float16 h = (_Float16)x[j];
            dst[base] = h;
            dst[base + 32] = (_Float16)(x[j] - (float)h);
        }
    } else {
        #pragma unroll
        for (int j = 0; j < 8; ++j)
            dst[(size_t)token * DM + lane + 64 * j] = (_Float16)x[j];
    }
    float d[8];
    #pragma unroll
    for (int e = 0; e < 8; ++e) {
        float a = 0.f;
        #pragma unroll
        for (int j = 0; j < 8; ++j) a += x[j] * rmLds[e * DM + lane + 64 * j];
        d[e] = a;
    }
    #pragma unroll
    for (int off = 32; off > 0; off >>= 1) {
        ss += __shfl_xor(ss, off);
        #pragma unroll
        for (int e = 0; e < 8; ++e) d[e] += __shfl_xor(d[e], off);
    }
    float inv = 1.f / fmaxf(sqrtf(ss), 1e-12f);
    float best = -1e30f, second = -1e30f; int be = 0, se = 0;
    #pragma unroll
    for (int e = 0; e < 8; ++e) {
        float de = d[e] * inv;
        if (de > best)        { second = best; se = be; best = de; be = e; }
        else if (de > second) { second = de; se = e; }
    }
    float z = expf(second - best);
    float w0 = 1.f / (1.f + z), w1 = z / (1.f + z);
    if (lane == 0) {
        key[token] = (unsigned char)be;
        key[NTOK + token] = (unsigned char)se;
        wts[token] = make_float2(w0, w1);
        bs[token] = make_float2(best, second);
    }
}

// =============================== bucket compaction ===============================
__global__ __launch_bounds__(256) void compact_kernel(
    const unsigned char* __restrict__ key,
    const float2* __restrict__ wts,
    const float2* __restrict__ bs,
    int* __restrict__ cnt,
    unsigned short* __restrict__ bkt,
    float* __restrict__ imp,
    float* __restrict__ vq_acc)
{
    int slot = blockIdx.x >> 3, e = blockIdx.x & 7;
    int chunk = blockIdx.y;
    const unsigned char* k = key + slot * NTOK;
    unsigned short* ob = bkt + (size_t)(slot * 8 + e) * NTOK;
    int tid = threadIdx.x, lane = tid & 63, w = tid >> 6;
    float wsum = 0.f, vqs = 0.f;
    for (int c = 0; c < 8; ++c) {
        int tok = chunk * 2048 + c * 256 + tid;
        bool m = (k[tok] == (unsigned char)e);
        unsigned long long mask = __ballot(m);
        int wcount = __popcll(mask);
        int wbase = 0;
        if (lane == 0 && wcount) wbase = atomicAdd(&cnt[slot * 8 + e], wcount);
        wbase = __shfl(wbase, 0);
        if (m) {
            int pre = __popcll(mask & ((1ull << lane) - 1ull));
            ob[wbase + pre] = (unsigned short)tok;
            float2 wp = wts[tok]; float2 b2 = bs[tok];
            float wv = slot ? wp.y : wp.x;
            wsum += wv;
            vqs  += wv * (slot ? b2.y : b2.x);
        }
    }
    #pragma unroll
    for (int off = 32; off > 0; off >>= 1) {
        wsum += __shfl_xor(wsum, off);
        vqs  += __shfl_xor(vqs, off);
    }
    __shared__ float rw[4], rv[4];
    if (lane == 0) { rw[w] = wsum; rv[w] = vqs; }
    __syncthreads();
    if (tid == 0) {
        atomicAdd(&imp[e], rw[0] + rw[1] + rw[2] + rw[3]);
        atomicAdd(vq_acc, -(rv[0] + rv[1] + rv[2] + rv[3]));
    }
}

// =============================== grouped GEMM — barrier-free, XCD-grouped, NO ATOMICS ===============================
// r8 structure (1 wave/block, wave-private 16KB LDS, zero s_barrier, counted
// vmcnt(16), A-reg double-buffer, XCD m-tile grouping) with the epilogue
// switched from 16.8M fp32 global atomics (the r5-r8 hidden limiter: memory-side
// RMW, WRITE_SIZE=2x output, ~100+us) to PLAIN STORES into per-slot partial
// buffers: each (slot, token, col) is written by exactly one block -> no race,
// bit-deterministic; the consumer sums P0+P1 (route1 fused / sum1 kernel).
// SPLIT passes: ah*bh, ah*bl, al*bh. Plain: a0*bh (k0..31), a1*bl (k32..63).
template <bool SPLIT>
__global__ __launch_bounds__(64) void gemm_kernel(
    const _Float16* __restrict__ A,      // SPLIT: xpk [tok][1024] ; else h16 [tok][512]
    const _Float16* __restrict__ Wpk,    // packed tiles
    const float* __restrict__ bias,      // [8][512]
    const float* __restrict__ iav,       // [8]
    const float* __restrict__ tscp,
    const int* __restrict__ cnt16,       // [16] this layer (slot*8+e)
    const unsigned short* __restrict__ bkt, // [16][16384] this layer
    const float2* __restrict__ wts,      // [16384]
    float* __restrict__ outP0,           // slot0 partial [16384][512]
    float* __restrict__ outP1)           // slot1 partial [16384][512]
{
    __shared__ __align__(16) _Float16 ldsB[2 * 4096];   // 16KB, wave-private
    __shared__ int tokLds[64];

    int bx = blockIdx.x;
    int xcd = bx & 7, sIdx = bx >> 3;
    int t = xcd * 66 + (sIdx >> 3), nt64 = sIdx & 7;
    int b = -1, m0 = 0, M = 0, acc0 = 0;
    #pragma unroll
    for (int bb = 0; bb < 16; ++bb) {
        int Me = cnt16[bb];
        int ne = (Me + 63) >> 6;
        if (t >= acc0 && t < acc0 + ne) { b = bb; m0 = (t - acc0) << 6; M = Me; }
        acc0 += ne;
    }
    if (b < 0) return;                    // t beyond total tiles
    int slot = b >> 3, e = b & 7;
    int n0 = nt64 << 6;
    int valid = min(64, M - m0);
    int lane = threadIdx.x;
    int q = lane >> 4, l15 = lane & 15;

    tokLds[lane] = bkt[(size_t)b * NTOK + m0 + min(lane, valid - 1)];

    constexpr int KIT = SPLIT ? 16 : 8;
    constexpr int AS  = SPLIT ? 1024 : 512;

    const _Float16* Ab[4];
    #pragma unroll
    for (int mi = 0; mi < 4; ++mi)
        Ab[mi] = A + (size_t)tokLds[mi * 16 + l15] * AS + q * 8;

    // packed W: 128-col tile nt64>>1, take the j-half (nt64&1)*8..+8
    const _Float16* wtile = Wpk + ((size_t)(e * 4 + (nt64 >> 1)) * KIT) * 8192
                                + (size_t)(nt64 & 1) * 8 * 512;

    floatx4 accu[4][4];
    #pragma unroll
    for (int mi = 0; mi < 4; ++mi)
        #pragma unroll
        for (int ni = 0; ni < 4; ++ni) accu[mi][ni] = (floatx4){0.f, 0.f, 0.f, 0.f};

    half8 ahR[2][4], alR[2][4];

    // prologue: A(0) -> reg set 0, B(0) -> LDS buf 0 (8 x 1KB contiguous copies)
    #pragma unroll
    for (int mi = 0; mi < 4; ++mi) {
        ahR[0][mi] = *(const half8*)(Ab[mi]);
        alR[0][mi] = *(const half8*)(Ab[mi] + 32);
    }
    #pragma unroll
    for (int jj = 0; jj < 8; ++jj)
        gl_lds16(wtile + jj * 512 + lane * 8, (void*)(ldsB + jj * 512));

    #pragma unroll
    for (int kb = 0; kb < KIT; ++kb) {
        int cu = kb & 1, nx = cu ^ 1;
        if (kb + 1 < KIT) {
            #pragma unroll
            for (int mi = 0; mi < 4; ++mi) {
                ahR[nx][mi] = *(const half8*)(Ab[mi] + (kb + 1) * 64);
                alR[nx][mi] = *(const half8*)(Ab[mi] + (kb + 1) * 64 + 32);
            }
            const _Float16* wb = wtile + (size_t)(kb + 1) * 8192;
            _Float16* dB = ldsB + nx * 4096;
            #pragma unroll
            for (int jj = 0; jj < 8; ++jj)
                gl_lds16(wb + jj * 512 + lane * 8, (void*)(dB + jj * 512));
            asm volatile("s_waitcnt vmcnt(16)" ::: "memory");   // retire iter-kb's 16 ops
        } else {
            asm volatile("s_waitcnt vmcnt(0)" ::: "memory");
        }
        __builtin_amdgcn_sched_barrier(0);
        {
            const _Float16* bB = ldsB + cu * 4096;
            #pragma unroll
            for (int ni = 0; ni < 4; ++ni) {
                int r = ni * 16 + l15;
                int ph = q ^ (r & 7), pl = (q + 4) ^ (r & 7);
                half8 bh = *(const half8*)(bB + r * 64 + ph * 8);
                half8 bl = *(const half8*)(bB + r * 64 + pl * 8);
                if constexpr (SPLIT) {
                    #pragma unroll
                    for (int mi = 0; mi < 4; ++mi) accu[mi][ni] = MFMA_F16(ahR[cu][mi], bh, accu[mi][ni]);
                    #pragma unroll
                    for (int mi = 0; mi < 4; ++mi) accu[mi][ni] = MFMA_F16(ahR[cu][mi], bl, accu[mi][ni]);
                    #pragma unroll
                    for (int mi = 0; mi < 4; ++mi) accu[mi][ni] = MFMA_F16(alR[cu][mi], bh, accu[mi][ni]);
                } else {
                    #pragma unroll
                    for (int mi = 0; mi < 4; ++mi) accu[mi][ni] = MFMA_F16(ahR[cu][mi], bh, accu[mi][ni]);
                    #pragma unroll
                    for (int mi = 0; mi < 4; ++mi) accu[mi][ni] = MFMA_F16(alR[cu][mi], bl, accu[mi][ni]);
                }
            }
        }
    }

    // epilogue: C/D layout col=lane&15, row=(lane>>4)*4+reg; PLAIN posted stores
    float tsc = *tscp, iae = iav[e];
    float* outP = slot ? outP1 : outP0;
    float bv[4];
    #pragma unroll
    for (int ni = 0; ni < 4; ++ni) bv[ni] = bias[e * DM + n0 + ni * 16 + l15];
    #pragma unroll
    for (int mi = 0; mi < 4; ++mi) {
        int liBase = mi * 16 + q * 4;
        #pragma unroll
        for (int reg = 0; reg < 4; ++reg) {
            int li = liBase + reg;
            if (li < valid) {
                int tok = tokLds[li];
                float2 wp = wts[tok];
                float wgt = slot ? wp.y : wp.x;
                float sg = tsc * wgt * iae, sb = tsc * wgt;
                float* orow = outP + (size_t)tok * DM + n0;
                #pragma unroll
                for (int ni = 0; ni < 4; ++ni) {
                    int c = ni * 16 + l15;
                    orow[c] = accu[mi][ni][reg] * sg + bv[ni] * sb;
                }
            }
        }
    }
}

// =============================== partial sum (h1 = Q0 + Q1, in place) ===============================
__global__ __launch_bounds__(256) void sum_kernel(
    const float4* __restrict__ a, const float4* __restrict__ b, float4* __restrict__ o)
{
    int i = blockIdx.x * 256 + threadIdx.x;     // 8192*256 = 2M float4 = 8.4M floats
    float4 va = a[i], vb = b[i];
    o[i] = make_float4(va.x + vb.x, va.y + vb.y, va.z + vb.z, va.w + vb.w);
}

// =============================== finalize aux ===============================
__global__ void finalize_kernel(const float* __restrict__ ctrl, float* __restrict__ outp)
{
    if (threadIdx.x == 0) {
        float aux = 0.f;
        for (int l = 0; l < 2; ++l) {
            float vq = ctrl[48 + l] / (float)NTOK;
            float mean = 0.f;
            for (int e = 0; e < 8; ++e) mean += ctrl[32 + l * 8 + e];
            mean *= 0.125f;
            float s = 0.f;
            for (int e = 0; e < 8; ++e) {
                float d = ctrl[32 + l * 8 + e] - mean;
                s += d * d;
            }
            float var = s / 7.f;                       // ddof=1
            float lb = var / (mean * mean + 1e-10f);
            aux += 0.05f * vq + 0.01f * lb;
        }
        *outp = aux;
    }
}

// =============================== launch ===============================
extern "C" void kernel_launch(void* const* d_in, const int* in_sizes, int n_in,
                              void* d_out, int out_size, void* d_ws, size_t ws_size,
                              hipStream_t stream) {
    const float* x     = (const float*)d_in[0];
    const float* rm0   = (const float*)d_in[1];
    const float* W0    = (const float*)d_in[2];
    const float* b0    = (const float*)d_in[3];
    const float* temp0 = (const float*)d_in[4];
    const float* ca0   = (const float*)d_in[5];
    const float* rm1   = (const float*)d_in[6];
    const float* W1    = (const float*)d_in[7];
    const float* b1    = (const float*)d_in[8];
    const float* temp1 = (const float*)d_in[9];
    const float* ca1   = (const float*)d_in[10];
    float* out = (float*)d_out;

    char* ws = (char*)d_ws;
    float* ctrl = (float*)ws;
    int*   cnt  = (int*)ctrl;                 // [2][16]
    float* imp  = ctrl + 32;                  // [2][8]
    float* vq   = ctrl + 48;                  // [2]
    float* tsc  = ctrl + 50;                  // [2]
    float* ia   = ctrl + 52;                  // [2][8]
    float* rmn  = ctrl + 128;                 // [16][512]
    float2*        wts = (float2*)(ws + (size_t)64  * 1024);
    float2*        bs  = (float2*)(ws + (size_t)384 * 1024);
    unsigned char* key = (unsigned char*)(ws + (size_t)704 * 1024);

    char* big = ws + (1 << 20);
    half8*          w0pk8 = (half8*)(big);                                 // 8MB
    half8*          w1pk8 = (half8*)(big + (size_t)8  * 1024 * 1024);      // 4MB
    const _Float16* w0pk  = (const _Float16*)w0pk8;
    const _Float16* w1pk  = (const _Float16*)w1pk8;
    _Float16*       h16   = (_Float16*)(big + (size_t)12 * 1024 * 1024);   // 16MB
    unsigned short* bkt   = (unsigned short*)(big + (size_t)28 * 1024 * 1024); // 2MB
    float*          Pbuf  = (float*)(big + (size_t)30 * 1024 * 1024);      // 32MB (ws tot 63MB)

    // d_out regions
    float*    P0  = out;                                  // h_emb region: P0 -> h_emb (in place)
    _Float16* xpk = (_Float16*)(out + (size_t)NTOK * DM); // h1 region: xpk ...
    float*    Q0  = out + (size_t)NTOK * DM;              // ... then Q0 -> h1 (in place)

    const int GEMM_GRID = 528 * 8;   // 8 XCDs x 66 t-slots x 8 n-tiles

    pack_w_kernel<<<3073, 256, 0, stream>>>(W0, W1, w0pk8, w1pk8,
        rm0, rm1, ca0, ca1, temp0, temp1, ctrl, rmn);

    // layer 0
    route_kernel<<<4096, 256, 0, stream>>>(x, (const float*)nullptr, rmn, 0, 1,
        xpk, (float*)nullptr, key, wts, bs);
    compact_kernel<<<dim3(16, 8), 256, 0, stream>>>(key, wts, bs, cnt, bkt, imp, vq);
    gemm_kernel<true><<<GEMM_GRID, 64, 0, stream>>>(xpk, w0pk, b0, ia, tsc,
        cnt, bkt, wts, P0, Pbuf);

    // layer 1: route fuses h0 = P0 + Pbuf, writes h_emb in place over P0
    route_kernel<<<4096, 256, 0, stream>>>(P0, Pbuf, rmn + 4096, 1, 0,
        h16, P0, key + 2 * NTOK, wts + NTOK, bs + NTOK);
    compact_kernel<<<dim3(16, 8), 256, 0, stream>>>(key + 2 * NTOK, wts + NTOK, bs + NTOK,
        cnt + 16, bkt + 16 * NTOK, imp + 8, vq + 1);
    gemm_kernel<false><<<GEMM_GRID, 64, 0, stream>>>(h16, w1pk, b1, ia + 8, tsc + 1,
        cnt + 16, bkt + 16 * NTOK, wts + NTOK, Q0, Pbuf);
    sum_kernel<<<8192, 256, 0, stream>>>((const float4*)Q0, (const float4*)Pbuf, (float4*)Q0);

    finalize_kernel<<<1, 64, 0, stream>>>(ctrl, out + (size_t)2 * NTOK * DM);
}